// Round 10
// baseline (349.451 us; speedup 1.0000x reference)
//
#include <hip/hip_runtime.h>
#include <stdint.h>

// out[b,o,m] = sum_i in[b,i,m] * w[i,o,m]  (complex, fp32)
// B=32, Ci=Co=128, M=64*65=4160. One float2 per complex element.
//
// R10 = R9 body (verbatim; passed, 0 bank conflicts) + PERSISTENT blocks
// with a dynamic atomic-ticket job queue (d_ws). Theory: R6/R8/R9 were all
// round-quantized (grid ~2.03x resident slots -> ceil=3 rounds, last round
// ~3% full). Dynamic tickets keep the machine full until jobs run out.
// Job = 32b x 32o x 8modes, 32 K-chunks; 2080 jobs; 1024 persistent blocks.
// Ticket order: 4 o-sibling jobs of one mode-group are consecutive ->
// concurrent-ish -> A slice L2/L3-shared.

typedef float f2 __attribute__((ext_vector_type(2)));

#define NB 32
#define CI 128
#define CO 128
#define OT 32
#define MODES 4160
#define MPB 8
#define KC 4
#define NCHUNK (CI / KC)               // 32
#define ABUF_F2 (KC * NB * MPB)        // 1024 f2 = 8 KB
#define WBUF_F2 (KC * OT * MPB)        // 1024 f2 = 8 KB
#define BUF_F2  (ABUF_F2 + WBUF_F2)    // 16 KB per buffer
#define NJOBS 2080

// acc.lo += a.lo*w.lo - a.hi*w.hi ; acc.hi += a.lo*w.hi + a.hi*w.lo
#define CFMA(acc, av, wv)                                                      \
  asm("v_pk_fma_f32 %0, %1, %2, %0 op_sel:[0,0,0] op_sel_hi:[0,1,1]"           \
      : "+v"(acc) : "v"(av), "v"(wv));                                         \
  asm("v_pk_fma_f32 %0, %1, %2, %0 op_sel:[1,1,0] op_sel_hi:[1,0,1] "          \
      "neg_lo:[1,0,0]"                                                         \
      : "+v"(acc) : "v"(av), "v"(wv));

#define VM_WAIT(N) asm volatile("s_waitcnt vmcnt(" #N ")" ::: "memory")

__device__ __forceinline__ void gload16(const f2* g, f2* l) {
    __builtin_amdgcn_global_load_lds(
        (const __attribute__((address_space(1))) uint32_t*)g,
        (__attribute__((address_space(3))) uint32_t*)l, 16, 0, 0);
}

// Stage phase PH (0..3) of a K-chunk: one 16B DMA per thread (verbatim R9).
template <int PH>
__device__ __forceinline__ void stage_phase(const f2* __restrict__ Ig,
                                            const f2* __restrict__ Wl,
                                            f2* dst, int t, int m0,
                                            int obase, int k0) {
    if constexpr (PH < 2) {
        const int j  = PH * 256 + t;
        const int kk = j >> 7, b = (j >> 2) & 31, mlp = j & 3;
        gload16(Ig + (size_t)(b * CI + k0 + kk) * MODES + m0 + mlp * 2,
                dst + j * 2);
    } else {
        const int j   = (PH - 2) * 256 + t;
        const int kk  = j >> 7, oph = (j >> 2) & 31, p = j & 3;
        const int sw  = (oph >> 3) & 3;
        const int o   = oph ^ (sw & 1);
        const int qg  = p ^ sw;
        gload16(Wl + (size_t)((k0 + kk) * CO + obase + o) * MODES + m0 + qg * 2,
                dst + ABUF_F2 + j * 2);
    }
}

__global__ void init_ticket(uint32_t* p) { *p = 0u; }

__global__ __launch_bounds__(256, 4)
void cmul2d_kernel(const f2* __restrict__ Ig,
                   const f2* __restrict__ Wl,
                   f2* __restrict__ Og,
                   uint32_t* __restrict__ tickets) {
    __shared__ f2 lds[2 * BUF_F2];   // 32 KB
    __shared__ int s_job;

    const int t  = threadIdx.x;
    const int ml = t & 7;      // mode lane
    const int s  = t >> 3;     // worker 0..31
    const int so = s & 3;      // o-group (8 o each)
    const int sb = s >> 2;     // b-group (4 b each)
    const int pxor = (ml >> 1);

    for (;;) {
        if (t == 0) s_job = (int)atomicAdd(tickets, 1u);
        __syncthreads();
        const int jid = s_job;
        if (jid >= NJOBS) break;

        // consecutive tickets = o-siblings of one mode-group (A locality)
        const int m0    = (jid >> 2) * MPB;
        const int obase = (jid & 3) * OT;

        f2 acc[4][8];
#pragma unroll
        for (int r = 0; r < 4; ++r)
#pragma unroll
            for (int q = 0; q < 8; ++q) acc[r][q] = (f2)(0.0f);

        // prologue: stage chunk 0 into buffer 0
        stage_phase<0>(Ig, Wl, lds, t, m0, obase, 0);
        stage_phase<1>(Ig, Wl, lds, t, m0, obase, 0);
        stage_phase<2>(Ig, Wl, lds, t, m0, obase, 0);
        stage_phase<3>(Ig, Wl, lds, t, m0, obase, 0);

#pragma unroll 1
        for (int c = 0; c < NCHUNK; ++c) {
            VM_WAIT(0);                    // own chunk-c loads retired
            __builtin_amdgcn_s_barrier();  // collective: chunk c in LDS
            __builtin_amdgcn_sched_barrier(0);

            const f2* Ab = lds + (c & 1) * BUF_F2;
            const f2* Wb = Ab + ABUF_F2;
            f2* nbuf = lds + ((c + 1) & 1) * BUF_F2;
            const bool more = (c + 1 < NCHUNK);
            const int  nk0  = (c + 1) * KC;

#pragma unroll
            for (int kk = 0; kk < KC; ++kk) {
                f2 a[4], w[8];
#pragma unroll
                for (int r = 0; r < 4; ++r)
                    a[r] = Ab[kk * (NB * MPB) + (sb * 4 + r) * MPB + ml];
#pragma unroll
                for (int q = 0; q < 8; ++q) {
                    const int o   = so * 8 + q;
                    const int oph = o ^ (so & 1);
                    const int p   = pxor ^ so;
                    w[q] = Wb[(kk * (OT * MPB)) + ((oph * 4 + p) << 1) + (ml & 1)];
                }
                if (more) {                // spread DMA: 1 per kk-phase
                    if (kk == 0) stage_phase<0>(Ig, Wl, nbuf, t, m0, obase, nk0);
                    else if (kk == 1) stage_phase<1>(Ig, Wl, nbuf, t, m0, obase, nk0);
                    else if (kk == 2) stage_phase<2>(Ig, Wl, nbuf, t, m0, obase, nk0);
                    else stage_phase<3>(Ig, Wl, nbuf, t, m0, obase, nk0);
                }
                __builtin_amdgcn_s_setprio(1);
#pragma unroll
                for (int r = 0; r < 4; ++r)
#pragma unroll
                    for (int q = 0; q < 8; ++q) {
                        CFMA(acc[r][q], a[r], w[q]);
                    }
                __builtin_amdgcn_s_setprio(0);
            }
            // next iter's top barrier is the sync point
        }

        // epilogue: per (b,o) the 8 ml lanes are consecutive -> 64B segments
#pragma unroll
        for (int r = 0; r < 4; ++r) {
            const int b = sb * 4 + r;
#pragma unroll
            for (int q = 0; q < 8; ++q) {
                const int o = obase + so * 8 + q;
                Og[(size_t)(b * CO + o) * MODES + m0 + ml] = acc[r][q];
            }
        }
        // loop: next ticket (s_job rewrite is safe -- jid already in regs,
        // and the next job's first s_barrier orders all waves)
    }
}

extern "C" void kernel_launch(void* const* d_in, const int* in_sizes, int n_in,
                              void* d_out, int out_size, void* d_ws, size_t ws_size,
                              hipStream_t stream) {
    const f2* I = (const f2*)d_in[0];
    const f2* W = (const f2*)d_in[1];
    f2* O = (f2*)d_out;
    uint32_t* tk = (uint32_t*)d_ws;
    init_ticket<<<1, 1, 0, stream>>>(tk);
    cmul2d_kernel<<<1024, 256, 0, stream>>>(I, W, O, tk);
}

// Round 11
// 262.810 us; speedup vs baseline: 1.3297x; 1.3297x over previous
//
#include <hip/hip_runtime.h>
#include <stdint.h>

// out[b,o,m] = sum_i in[b,i,m] * w[i,o,m]  (complex, fp32)
// B=32, Ci=Co=128, M=64*65=4160. One float2 per complex element.
//
// R11: quantization fix. R6/R8/R9 all ran N ~= 2.03 x resident-slots ->
// ceil = 3 rounds -> 67% util (the "3.2 TB/s plateau" was never BW).
// Now: OT=16 -> 24KB LDS -> 6 blocks/CU (S~1536), N = 4160 jobs ->
// 3 rounds at 90% util. Job = 32b x 16o x 8modes, 256 thr, tile 4b x 4o.
// Pipeline = R9's proven body (spread gload_lds DMA, 1 barrier/chunk,
// VM_WAIT(0) on own chunk, setprio around FMA).
// W swizzle REVERTED to single-XOR (R9's two-level one caused the 8.5M
// conflicts seen in R10): phys o' = o ^ ((o>>2)&1), both sides -> 2-way.
// Static XCD map: 8 o-siblings of a mode-group adjacent per XCD -> A
// slice (256KB) L2-shared; A total 136MB < L3 -> re-reads never hit HBM.

typedef float f2 __attribute__((ext_vector_type(2)));

#define NB 32
#define CI 128
#define CO 128
#define OT 16
#define MODES 4160
#define MPB 8
#define KC 4
#define NCHUNK (CI / KC)               // 32
#define ABUF_F2 (KC * NB * MPB)        // 1024 f2 = 8 KB
#define WBUF_F2 (KC * OT * MPB)        //  512 f2 = 4 KB
#define BUF_F2  (ABUF_F2 + WBUF_F2)    // 12 KB per buffer

// acc.lo += a.lo*w.lo - a.hi*w.hi ; acc.hi += a.lo*w.hi + a.hi*w.lo
#define CFMA(acc, av, wv)                                                      \
  asm("v_pk_fma_f32 %0, %1, %2, %0 op_sel:[0,0,0] op_sel_hi:[0,1,1]"           \
      : "+v"(acc) : "v"(av), "v"(wv));                                         \
  asm("v_pk_fma_f32 %0, %1, %2, %0 op_sel:[1,1,0] op_sel_hi:[1,0,1] "          \
      "neg_lo:[1,0,0]"                                                         \
      : "+v"(acc) : "v"(av), "v"(wv));

#define VM_WAIT(N) asm volatile("s_waitcnt vmcnt(" #N ")" ::: "memory")

__device__ __forceinline__ void gload16(const f2* g, f2* l) {
    __builtin_amdgcn_global_load_lds(
        (const __attribute__((address_space(1))) uint32_t*)g,
        (__attribute__((address_space(3))) uint32_t*)l, 16, 0, 0);
}

// Stage one K-chunk = 3 x 16B DMA units per thread.
// A (512 units, U=0,1): u = U*256+t <-> kk=u>>7, b=(u>>2)&31, mu=u&3.
//   LDS f2 slot = u*2 (linear).
// W (256 units, U=2): t <-> kk=t>>6, oph=(t>>2)&15, mu=t&3. Physical row
//   oph holds logical o = oph ^ ((oph>>2)&1) (involution, both sides).
template <int U>
__device__ __forceinline__ void stage_unit(const f2* __restrict__ Ig,
                                           const f2* __restrict__ Wl,
                                           f2* dst, int t, int m0,
                                           int obase, int k0) {
    if constexpr (U < 2) {
        const int u  = U * 256 + t;
        const int kk = u >> 7, b = (u >> 2) & 31, mu = u & 3;
        gload16(Ig + (size_t)(b * CI + k0 + kk) * MODES + m0 + mu * 2,
                dst + u * 2);
    } else {
        const int kk = t >> 6, oph = (t >> 2) & 15, mu = t & 3;
        const int o  = oph ^ ((oph >> 2) & 1);
        gload16(Wl + (size_t)((k0 + kk) * CO + obase + o) * MODES + m0 + mu * 2,
                dst + ABUF_F2 + t * 2);
    }
}

__global__ __launch_bounds__(256, 6)
void cmul2d_kernel(const f2* __restrict__ Ig,
                   const f2* __restrict__ Wl,
                   f2* __restrict__ Og) {
    __shared__ f2 lds[2 * BUF_F2];   // 24 KB -> 6 blocks/CU

    const int t   = threadIdx.x;
    const int bid = blockIdx.x;

    // static XCD map: 4160 = 8 XCD-groups x 520; within a group the 8
    // o-sibling jobs of one mode-group are temporally adjacent.
    const int g   = bid & 7;
    const int l   = bid >> 3;            // 0..519
    const int mgl = l >> 3;              // 0..64
    const int oj  = l & 7;               // o-sixteenth
    const int m0    = (g * 65 + mgl) * MPB;
    const int obase = oj * OT;

    const int ml = t & 7;      // mode lane
    const int s  = t >> 3;     // worker 0..31
    const int so = s & 3;      // o-group (4 o each)
    const int sb = s >> 2;     // b-group (4 b each)

    f2 acc[4][4];
#pragma unroll
    for (int r = 0; r < 4; ++r)
#pragma unroll
        for (int q = 0; q < 4; ++q) acc[r][q] = (f2)(0.0f);

    // prologue: stage chunk 0 into buffer 0
    stage_unit<0>(Ig, Wl, lds, t, m0, obase, 0);
    stage_unit<1>(Ig, Wl, lds, t, m0, obase, 0);
    stage_unit<2>(Ig, Wl, lds, t, m0, obase, 0);

#pragma unroll 1
    for (int c = 0; c < NCHUNK; ++c) {
        VM_WAIT(0);                       // own chunk-c DMAs retired
        __builtin_amdgcn_s_barrier();     // collective: chunk c in LDS
        __builtin_amdgcn_sched_barrier(0);

        const f2* Ab = lds + (c & 1) * BUF_F2;
        const f2* Wb = Ab + ABUF_F2;
        f2* nbuf = lds + ((c + 1) & 1) * BUF_F2;  // readers done (barrier)
        const bool more = (c + 1 < NCHUNK);
        const int  nk0  = (c + 1) * KC;

#pragma unroll
        for (int kk = 0; kk < KC; ++kk) {
            f2 a[4], w[4];
#pragma unroll
            for (int r = 0; r < 4; ++r)   // 2-way broadcast: free
                a[r] = Ab[kk * (NB * MPB) + (sb * 4 + r) * MPB + ml];
#pragma unroll
            for (int q = 0; q < 4; ++q) { // single-XOR swizzle: 2-way, free
                const int oph = (so * 4 + q) ^ (so & 1);
                w[q] = Wb[kk * (OT * MPB) + oph * MPB + ml];
            }
            if (more) {                   // spread DMA: 1 unit per kk-phase
                if (kk == 0) stage_unit<0>(Ig, Wl, nbuf, t, m0, obase, nk0);
                else if (kk == 1) stage_unit<1>(Ig, Wl, nbuf, t, m0, obase, nk0);
                else if (kk == 2) stage_unit<2>(Ig, Wl, nbuf, t, m0, obase, nk0);
            }
            __builtin_amdgcn_s_setprio(1);
#pragma unroll
            for (int r = 0; r < 4; ++r)
#pragma unroll
                for (int q = 0; q < 4; ++q) {
                    CFMA(acc[r][q], a[r], w[q]);
                }
            __builtin_amdgcn_s_setprio(0);
        }
        // next iter's top barrier is the sync point (no trailing barrier)
    }

    // epilogue: per (b,o) the 8 ml lanes are consecutive -> 64B segments
#pragma unroll
    for (int r = 0; r < 4; ++r) {
        const int b = sb * 4 + r;
#pragma unroll
        for (int q = 0; q < 4; ++q) {
            const int o = obase + so * 4 + q;
            Og[(size_t)(b * CO + o) * MODES + m0 + ml] = acc[r][q];
        }
    }
}

extern "C" void kernel_launch(void* const* d_in, const int* in_sizes, int n_in,
                              void* d_out, int out_size, void* d_ws, size_t ws_size,
                              hipStream_t stream) {
    const f2* I = (const f2*)d_in[0];
    const f2* W = (const f2*)d_in[1];
    f2* O = (f2*)d_out;
    dim3 grid(4160);   // 520 mode-groups x 8 o-sixteenths, XCD-grouped
    dim3 block(256);
    cmul2d_kernel<<<grid, block, 0, stream>>>(I, W, O);
}